// Round 12
// baseline (3023.011 us; speedup 1.0000x reference)
//
#include <hip/hip_runtime.h>
#include <hip/hip_bf16.h>

#define MDIM 4096
#define DDIM 2048
#define HDIM 2048
#define EDIM 8
#define HD   ((size_t)HDIM * DDIM)

typedef float v4f __attribute__((ext_vector_type(4)));
typedef int   v4i __attribute__((ext_vector_type(4)));
typedef int   v8i __attribute__((ext_vector_type(8)));

// async global->LDS, 16B per lane. lds pointer must be wave-uniform
// (HW writes base + lane*16).
__device__ __forceinline__ void gl2lds16(const void* g, void* l) {
  __builtin_amdgcn_global_load_lds(
      (const __attribute__((address_space(1))) void*)g,
      (__attribute__((address_space(3))) void*)l,
      16, 0, 0);
}

// ---------------- Kernel 1: gating softmax + fp8 quantize of x ----------------
__global__ __launch_bounds__(256) void k_gate_xq(
    const float* __restrict__ x, const float* __restrict__ gw,
    const float* __restrict__ gb, float* __restrict__ gate,
    unsigned char* __restrict__ x8)
{
  const int wid  = threadIdx.x >> 6;
  const int lane = threadIdx.x & 63;
  const int m    = blockIdx.x * 4 + wid;

  const float4* xr = (const float4*)(x + (size_t)m * DDIM);
  unsigned int* qr = (unsigned int*)(x8 + (size_t)m * DDIM);

  float part[EDIM];
#pragma unroll
  for (int e = 0; e < EDIM; ++e) part[e] = 0.f;

#pragma unroll
  for (int it = 0; it < DDIM / 4 / 64; ++it) {   // 8 iterations
    const int idx = it * 64 + lane;
    const float4 xv = xr[idx];
    int pk = __builtin_amdgcn_cvt_pk_fp8_f32(xv.x, xv.y, 0, false);
    pk = __builtin_amdgcn_cvt_pk_fp8_f32(xv.z, xv.w, pk, true);
    qr[idx] = (unsigned int)pk;
#pragma unroll
    for (int e = 0; e < EDIM; ++e) {
      const float4 wv = ((const float4*)(gw + (size_t)e * DDIM))[idx];
      part[e] += xv.x * wv.x + xv.y * wv.y + xv.z * wv.z + xv.w * wv.w;
    }
  }
#pragma unroll
  for (int e = 0; e < EDIM; ++e) {
#pragma unroll
    for (int off = 32; off > 0; off >>= 1)
      part[e] += __shfl_xor(part[e], off);
  }
  float lg[EDIM];
  float s = 0.f;
#pragma unroll
  for (int e = 0; e < EDIM; ++e) lg[e] = part[e] + gb[e];
  float mx = lg[0];
#pragma unroll
  for (int e = 1; e < EDIM; ++e) mx = fmaxf(mx, lg[e]);
#pragma unroll
  for (int e = 0; e < EDIM; ++e) { lg[e] = expf(lg[e] - mx); s += lg[e]; }
  const float inv = 1.f / s;
  if (lane < EDIM) gate[m * EDIM + lane] = lg[lane] * inv;
}

// ---------------- Kernel 2: fp8 quantize of expert_w --------------------------
__global__ void k_wq(const float* __restrict__ w, unsigned char* __restrict__ w8)
{
  const long long n4 = (long long)EDIM * HDIM * DDIM / 4;
  const long long stride = (long long)gridDim.x * blockDim.x;
  for (long long i = (long long)blockIdx.x * blockDim.x + threadIdx.x; i < n4;
       i += stride) {
    const float4 v = ((const float4*)w)[i];
    int pk = __builtin_amdgcn_cvt_pk_fp8_f32(v.x, v.y, 0, false);
    pk = __builtin_amdgcn_cvt_pk_fp8_f32(v.z, v.w, pk, true);
    ((unsigned int*)w8)[i] = (unsigned int)pk;
  }
}

// ---------------- Kernel 3: fused grouped GEMM + gated combine ----------------
// R11 geometry (tile 128x128, 512 blocks = 2/CU, 256 thr, 4 waves 2m x 2n,
// 64x64/wave, dbuf global_load_lds + both-sides XOR swizzle) with the loop
// nest INVERTED: k-tile outer, expert inner. av[4] is read from LDS once per
// k-tile and reused for all 8 experts (gate-FMA per (k,e): outacc +=
// g_e * mfma(A,B_e,0); numerics validated R5/R6/R8, absmax 0.015625).
// LDS reads/wave/k-tile: A 128B/lane + 8x B 128B/lane = 1152B vs R11's
// 2048B -> 114 FLOP/LDS-byte (1.78x); per-CU step LDS ~= MFMA cycles.
// Regs ~190 total (outacc 64 + av 32 + bv 32 + g 16 + misc) < 256 ->
// 2 waves/SIMD (two independent blocks) preserved.
// vmcnt schedule (B staged every step, A once per 8, B issued BEFORE A at
// e0 so B retires first): waits 8,8,4,4,4,4,4,4; kt=15 tail 4,...,4,0.
__global__ __launch_bounds__(256, 2) void k_moe_gemm(
    const unsigned char* __restrict__ x8,   // [M, D]
    const unsigned char* __restrict__ w8,   // [E, H, D]
    const float* __restrict__ gate,         // [M, 8]
    float* __restrict__ out)                // [M, H] f32
{
  extern __shared__ unsigned char smem[];   // 2*16K A + 2*16K B + 4K G = 68K

  const int tid  = threadIdx.x;
  const int lane = tid & 63;
  const int wid  = tid >> 6;        // 0..3
  const int wm   = wid >> 1;        // 0..1  (64-row group)
  const int wn   = wid & 1;         // 0..1  (64-col group)

  // XCD chunking: 512 blocks; each XCD owns an 8x8 square of (m,h) tiles.
  const int bid   = blockIdx.x;
  const int xcd   = bid & 7;
  const int local = bid >> 3;                        // 0..63
  const int tm    = (xcd >> 1) * 8 + (local >> 3);   // 0..31
  const int tn    = (xcd & 1) * 8 + (local & 7);     // 0..15
  const int bm    = tm * 128;
  const int bn    = tn * 128;

  const int lrow = lane & 15;
  const int lk   = lane >> 4;                  // 0..3 -> 32B k-block
  const int c0   = (lk * 32) ^ ((lrow & 7) << 4);
  const int c1   = c0 ^ 16;

  // staging coords: thread covers row strow of each 32-row slab,
  // inverse-swizzled col stcol (involution within the 128B row).
  const int strow = tid >> 3;                  // 0..31
  const int stcol = ((tid & 7) * 16) ^ ((strow & 7) << 4);
  const unsigned char* asrc = x8 + (size_t)(bm + strow) * DDIM + stcol;
  const unsigned char* bsrc = w8 + (size_t)(bn + strow) * DDIM + stcol;

  float* sGf = (float*)(smem + 65536);         // [8 experts][128 rows]

  // gate cache: threads 0..127 own row bm+tid for all 8 experts
  if (tid < 128) {
    const float4 g0 = *(const float4*)(gate + (size_t)(bm + tid) * EDIM);
    const float4 g1 = *(const float4*)(gate + (size_t)(bm + tid) * EDIM + 4);
    sGf[0 * 128 + tid] = g0.x; sGf[1 * 128 + tid] = g0.y;
    sGf[2 * 128 + tid] = g0.z; sGf[3 * 128 + tid] = g0.w;
    sGf[4 * 128 + tid] = g1.x; sGf[5 * 128 + tid] = g1.y;
    sGf[6 * 128 + tid] = g1.z; sGf[7 * 128 + tid] = g1.w;
  }

  v4f outacc[4][4];   // gated running sum
#pragma unroll
  for (int i = 0; i < 4; ++i)
#pragma unroll
    for (int j = 0; j < 4; ++j) {
      outacc[i][j][0] = 0.f; outacc[i][j][1] = 0.f;
      outacc[i][j][2] = 0.f; outacc[i][j][3] = 0.f;
    }
  v8i av[4];          // A fragments, loaded once per k-tile, 8x reuse
  const v4f zero4 = {0.f, 0.f, 0.f, 0.f};

// stage A k-tile KT into abuf[KT&1]: 4 loads/thread
#define STAGE_A(KT) do {                                                       \
    const int kb_ = (KT) * 128;                                                \
    unsigned char* la_ = smem + ((KT) & 1) * 16384;                            \
    _Pragma("unroll") for (int i = 0; i < 4; ++i)                              \
      gl2lds16(asrc + (size_t)i * (32 * DDIM) + kb_,                           \
               (void*)(la_ + i * 4096 + wid * 1024));                          \
  } while (0)

// stage B tile (expert E, k-tile KT) into bbuf[(E)&1]: 4 loads/thread
#define STAGE_B(KT, E) do {                                                    \
    const size_t o_ = (size_t)(E) * HD + (size_t)((KT) * 128);                 \
    unsigned char* lb_ = smem + 32768 + ((E) & 1) * 16384;                     \
    _Pragma("unroll") for (int i = 0; i < 4; ++i)                              \
      gl2lds16(bsrc + (size_t)i * (32 * DDIM) + o_,                            \
               (void*)(lb_ + i * 4096 + wid * 1024));                          \
  } while (0)

// A fragments LDS -> registers (once per k-tile)
#define LOADA(KT) do {                                                         \
    const unsigned char* pA_ = smem + ((KT) & 1) * 16384 +                     \
                               (size_t)(wm * 64 + lrow) * 128;                 \
    _Pragma("unroll") for (int f = 0; f < 4; ++f) {                            \
      union { v8i v; v4i h[2]; } u_;                                           \
      u_.h[0] = *(const v4i*)(pA_ + f * 2048 + c0);                            \
      u_.h[1] = *(const v4i*)(pA_ + f * 2048 + c1);                            \
      av[f] = u_.v;                                                            \
    }                                                                          \
  } while (0)

// one expert's B against the resident av[4]; gate-FMA into outacc
#define COMP(E) do {                                                           \
    const unsigned char* pB_ = smem + 32768 + ((E) & 1) * 16384 +              \
                               (size_t)(wn * 64 + lrow) * 128;                 \
    v4f g4_[4];                                                                \
    _Pragma("unroll") for (int i = 0; i < 4; ++i)                              \
      g4_[i] = *(const v4f*)(sGf + (E) * 128 + wm * 64 + i * 16 + lk * 4);     \
    v8i bv_[4];                                                                \
    _Pragma("unroll") for (int j = 0; j < 4; ++j) {                            \
      union { v8i v; v4i h[2]; } u_;                                           \
      u_.h[0] = *(const v4i*)(pB_ + j * 2048 + c0);                            \
      u_.h[1] = *(const v4i*)(pB_ + j * 2048 + c1);                            \
      bv_[j] = u_.v;                                                           \
    }                                                                          \
    __builtin_amdgcn_s_setprio(1);                                             \
    _Pragma("unroll") for (int i = 0; i < 4; ++i)                              \
      _Pragma("unroll") for (int j = 0; j < 4; ++j) {                          \
        const v4f t_ = __builtin_amdgcn_mfma_scale_f32_16x16x128_f8f6f4(       \
            av[i], bv_[j], zero4, 0 /*fp8*/, 0 /*fp8*/,                        \
            0, 127 /*e8m0 1.0*/, 0, 127 /*e8m0 1.0*/);                         \
        outacc[i][j][0] += g4_[i][0] * t_[0];                                  \
        outacc[i][j][1] += g4_[i][1] * t_[1];                                  \
        outacc[i][j][2] += g4_[i][2] * t_[2];                                  \
        outacc[i][j][3] += g4_[i][3] * t_[3];                                  \
      }                                                                        \
    __builtin_amdgcn_s_setprio(0);                                             \
  } while (0)

// one (kt, e) step. DOA: stage A(kt+1). DOB: stage next B. DOL: LOADA(kt).
#define KSTEP(KT, E, WAIT, DOB, DOA) do {                                      \
    if (DOB) { if ((E) < 7) STAGE_B((KT), (E) + 1);                            \
               else        STAGE_B((KT) + 1, 0); }                             \
    if (DOA) STAGE_A((KT) + 1);                                                \
    asm volatile("s_waitcnt vmcnt(" #WAIT ")" ::: "memory");                   \
    __builtin_amdgcn_s_barrier();                                              \
    __builtin_amdgcn_sched_barrier(0);                                         \
    if ((E) == 0) LOADA(KT);                                                   \
    COMP(E);                                                                   \
    __builtin_amdgcn_sched_barrier(0);                                         \
    __builtin_amdgcn_s_barrier();                                              \
  } while (0)

  STAGE_A(0);
  STAGE_B(0, 0);
  __syncthreads();   // drains prologue loads + publishes sGf (once)

  for (int kt = 0; kt < 15; ++kt) {
    KSTEP(kt, 0, 8, 1, 1);
    KSTEP(kt, 1, 8, 1, 0);
    KSTEP(kt, 2, 4, 1, 0);
    KSTEP(kt, 3, 4, 1, 0);
    KSTEP(kt, 4, 4, 1, 0);
    KSTEP(kt, 5, 4, 1, 0);
    KSTEP(kt, 6, 4, 1, 0);
    KSTEP(kt, 7, 4, 1, 0);
  }
  // kt = 15 tail: no A prefetch; last step drains to 0
  KSTEP(15, 0, 4, 1, 0);
  KSTEP(15, 1, 4, 1, 0);
  KSTEP(15, 2, 4, 1, 0);
  KSTEP(15, 3, 4, 1, 0);
  KSTEP(15, 4, 4, 1, 0);
  KSTEP(15, 5, 4, 1, 0);
  KSTEP(15, 6, 4, 1, 0);
  KSTEP(15, 7, 0, 0, 0);

#undef KSTEP
#undef COMP
#undef LOADA
#undef STAGE_B
#undef STAGE_A

  // epilogue: direct coalesced stores (single block per output tile)
#pragma unroll
  for (int i = 0; i < 4; ++i)
#pragma unroll
    for (int q = 0; q < 4; ++q) {
      const size_t r = (size_t)(bm + wm * 64 + i * 16 + lk * 4 + q);
      float* orow = out + r * HDIM + bn + wn * 64 + lrow;
#pragma unroll
      for (int j = 0; j < 4; ++j)
        orow[j * 16] = outacc[i][j][q];
    }
}

extern "C" void kernel_launch(void* const* d_in, const int* in_sizes, int n_in,
                              void* d_out, int out_size, void* d_ws, size_t ws_size,
                              hipStream_t stream) {
  (void)in_sizes; (void)n_in; (void)out_size; (void)ws_size;
  const float* x        = (const float*)d_in[0];
  const float* gate_w   = (const float*)d_in[1];
  const float* gate_b   = (const float*)d_in[2];
  const float* expert_w = (const float*)d_in[3];
  float* out = (float*)d_out;

  char* ws = (char*)d_ws;
  float* gate       = (float*)ws;                                   // 131072 B
  unsigned char* x8 = (unsigned char*)(ws + 131072);                // 8 MiB
  unsigned char* w8 = (unsigned char*)(ws + 131072 + (size_t)MDIM * DDIM);

  hipLaunchKernelGGL(k_gate_xq, dim3(MDIM / 4), dim3(256), 0, stream,
                     x, gate_w, gate_b, gate, x8);
  hipLaunchKernelGGL(k_wq, dim3(4096), dim3(256), 0, stream, expert_w, w8);
  hipLaunchKernelGGL(k_moe_gemm, dim3(512), dim3(256), 69632, stream,
                     x8, w8, gate, out);
}

// Round 13
// 2974.752 us; speedup vs baseline: 1.0162x; 1.0162x over previous
//
#include <hip/hip_runtime.h>
#include <hip/hip_bf16.h>

#define MDIM 4096
#define DDIM 2048
#define HDIM 2048
#define EDIM 8
#define HD   ((size_t)HDIM * DDIM)

typedef float v4f __attribute__((ext_vector_type(4)));
typedef int   v4i __attribute__((ext_vector_type(4)));
typedef int   v8i __attribute__((ext_vector_type(8)));

// async global->LDS, 16B per lane. lds pointer must be wave-uniform
// (HW writes base + lane*16).
__device__ __forceinline__ void gl2lds16(const void* g, void* l) {
  __builtin_amdgcn_global_load_lds(
      (const __attribute__((address_space(1))) void*)g,
      (__attribute__((address_space(3))) void*)l,
      16, 0, 0);
}

// ---------------- Kernel 1: gating softmax + fp8 quantize of x ----------------
__global__ __launch_bounds__(256) void k_gate_xq(
    const float* __restrict__ x, const float* __restrict__ gw,
    const float* __restrict__ gb, float* __restrict__ gate,
    unsigned char* __restrict__ x8)
{
  const int wid  = threadIdx.x >> 6;
  const int lane = threadIdx.x & 63;
  const int m    = blockIdx.x * 4 + wid;

  const float4* xr = (const float4*)(x + (size_t)m * DDIM);
  unsigned int* qr = (unsigned int*)(x8 + (size_t)m * DDIM);

  float part[EDIM];
#pragma unroll
  for (int e = 0; e < EDIM; ++e) part[e] = 0.f;

#pragma unroll
  for (int it = 0; it < DDIM / 4 / 64; ++it) {   // 8 iterations
    const int idx = it * 64 + lane;
    const float4 xv = xr[idx];
    int pk = __builtin_amdgcn_cvt_pk_fp8_f32(xv.x, xv.y, 0, false);
    pk = __builtin_amdgcn_cvt_pk_fp8_f32(xv.z, xv.w, pk, true);
    qr[idx] = (unsigned int)pk;
#pragma unroll
    for (int e = 0; e < EDIM; ++e) {
      const float4 wv = ((const float4*)(gw + (size_t)e * DDIM))[idx];
      part[e] += xv.x * wv.x + xv.y * wv.y + xv.z * wv.z + xv.w * wv.w;
    }
  }
#pragma unroll
  for (int e = 0; e < EDIM; ++e) {
#pragma unroll
    for (int off = 32; off > 0; off >>= 1)
      part[e] += __shfl_xor(part[e], off);
  }
  float lg[EDIM];
  float s = 0.f;
#pragma unroll
  for (int e = 0; e < EDIM; ++e) lg[e] = part[e] + gb[e];
  float mx = lg[0];
#pragma unroll
  for (int e = 1; e < EDIM; ++e) mx = fmaxf(mx, lg[e]);
#pragma unroll
  for (int e = 0; e < EDIM; ++e) { lg[e] = expf(lg[e] - mx); s += lg[e]; }
  const float inv = 1.f / s;
  if (lane < EDIM) gate[m * EDIM + lane] = lg[lane] * inv;
}

// ---------------- Kernel 2: fp8 quantize of expert_w --------------------------
__global__ void k_wq(const float* __restrict__ w, unsigned char* __restrict__ w8)
{
  const long long n4 = (long long)EDIM * HDIM * DDIM / 4;
  const long long stride = (long long)gridDim.x * blockDim.x;
  for (long long i = (long long)blockIdx.x * blockDim.x + threadIdx.x; i < n4;
       i += stride) {
    const float4 v = ((const float4*)w)[i];
    int pk = __builtin_amdgcn_cvt_pk_fp8_f32(v.x, v.y, 0, false);
    pk = __builtin_amdgcn_cvt_pk_fp8_f32(v.z, v.w, pk, true);
    ((unsigned int*)w8)[i] = (unsigned int)pk;
  }
}

// ---------------- Kernel 3: fused grouped GEMM + gated combine ----------------
// Barrier-minimal hybrid: A staged in LDS (dbuf, global_load_lds, both-sides
// XOR swizzle, once per k-tile); B loaded DIRECT global->VGPR inside a
// fence-free expert loop. 16 barriers total (one per k-tile) vs R11's 256.
// 256 thr (4 waves 2m x 2n, 64x64/wave), tile 128x128, grid 512 = 2
// independent blocks/CU (their stalls interleave).
// Loop-carried state discipline (R5..R12 lesson): only outacc (AGPR-foldable)
// crosses fences; av is loaded AFTER the k-tile barrier and dead before the
// next -> crosses zero fences (R12's spill trigger removed).
// Race safety: STAGE_A(kt+1) writes buf[(kt+1)&1] strictly after barrier(kt);
// every wave's LOADA(kt-1) reads of that buffer completed before barrier(kt).
// Numerics: per-(kt,e) gate-FMA outacc += g_e * mfma(A,B_e,0) (skips bf16
// rounding of y; bounded ~2^-9*|y|; absmax 0.015625 in R6/R8/R9/R12).
__global__ __launch_bounds__(256, 2) void k_moe_gemm(
    const unsigned char* __restrict__ x8,   // [M, D]
    const unsigned char* __restrict__ w8,   // [E, H, D]
    const float* __restrict__ gate,         // [M, 8]
    float* __restrict__ out)                // [M, H] f32
{
  extern __shared__ unsigned char smem[];   // 2*16K A + 4K gates = 36864 B

  const int tid  = threadIdx.x;
  const int lane = tid & 63;
  const int wid  = tid >> 6;        // 0..3
  const int wm   = wid >> 1;        // 0..1  (64-row group)
  const int wn   = wid & 1;         // 0..1  (64-col group)

  // XCD chunking: 512 blocks; each XCD owns an 8x8 square of (m,h) tiles.
  const int bid   = blockIdx.x;
  const int xcd   = bid & 7;
  const int local = bid >> 3;                        // 0..63
  const int tm    = (xcd >> 1) * 8 + (local >> 3);   // 0..31
  const int tn    = (xcd & 1) * 8 + (local & 7);     // 0..15
  const int bm    = tm * 128;
  const int bn    = tn * 128;

  const int lrow = lane & 15;
  const int lk   = lane >> 4;                  // 0..3 -> 32B k-block
  const int c0   = (lk * 32) ^ ((lrow & 7) << 4);   // swizzled A read cols
  const int c1   = c0 ^ 16;

  // A staging coords (inverse-swizzled source; LDS dest linear)
  const int strow = tid >> 3;                  // 0..31
  const int stcol = ((tid & 7) * 16) ^ ((strow & 7) << 4);
  const unsigned char* asrc = x8 + (size_t)(bm + strow) * DDIM + stcol;

  // B fragment base pointer (per lane, direct global)
  const unsigned char* bptr =
      w8 + (size_t)(bn + wn * 64 + lrow) * DDIM + lk * 32;

  float* sGf = (float*)(smem + 32768);         // [8 experts][128 rows]

  // gate cache: threads 0..127 own row bm+tid for all 8 experts
  if (tid < 128) {
    const float4 g0 = *(const float4*)(gate + (size_t)(bm + tid) * EDIM);
    const float4 g1 = *(const float4*)(gate + (size_t)(bm + tid) * EDIM + 4);
    sGf[0 * 128 + tid] = g0.x; sGf[1 * 128 + tid] = g0.y;
    sGf[2 * 128 + tid] = g0.z; sGf[3 * 128 + tid] = g0.w;
    sGf[4 * 128 + tid] = g1.x; sGf[5 * 128 + tid] = g1.y;
    sGf[6 * 128 + tid] = g1.z; sGf[7 * 128 + tid] = g1.w;
  }

  v4f outacc[4][4];   // gated running sum (AGPR-foldable, R11-proven)
#pragma unroll
  for (int i = 0; i < 4; ++i)
#pragma unroll
    for (int j = 0; j < 4; ++j) {
      outacc[i][j][0] = 0.f; outacc[i][j][1] = 0.f;
      outacc[i][j][2] = 0.f; outacc[i][j][3] = 0.f;
    }
  const v4f zero4 = {0.f, 0.f, 0.f, 0.f};

// stage A k-tile KT into abuf[KT&1]: 4 gl2lds16/thread
#define STAGE_A(KT) do {                                                       \
    const int kb_ = (KT) * 128;                                                \
    unsigned char* la_ = smem + ((KT) & 1) * 16384;                            \
    _Pragma("unroll") for (int i = 0; i < 4; ++i)                              \
      gl2lds16(asrc + (size_t)i * (32 * DDIM) + kb_,                           \
               (void*)(la_ + i * 4096 + wid * 1024));                          \
  } while (0)

  // prologue: stage A(0); publish gates; drain
  STAGE_A(0);
  __syncthreads();

  for (int kt = 0; kt < 16; ++kt) {
    // A(kt) loads were issued a full k-tile ago; all B loads already consumed.
    asm volatile("s_waitcnt vmcnt(0)" ::: "memory");
    __builtin_amdgcn_s_barrier();

    // A fragments for this k-tile (intra-region; crosses no fence)
    v8i av[4];
    {
      const unsigned char* pA = smem + (kt & 1) * 16384 +
                                (size_t)(wm * 64 + lrow) * 128;
#pragma unroll
      for (int f = 0; f < 4; ++f) {
        union { v8i v; v4i h[2]; } u;
        u.h[0] = *(const v4i*)(pA + f * 2048 + c0);
        u.h[1] = *(const v4i*)(pA + f * 2048 + c1);
        av[f] = u.v;
      }
    }
    if (kt < 15) STAGE_A(kt + 1);   // strictly after barrier(kt): race-free

    // fence-free expert loop: direct-global B + mfma + gate-FMA
#pragma unroll
    for (int e = 0; e < EDIM; ++e) {
      v4f g4[4];
#pragma unroll
      for (int i = 0; i < 4; ++i)
        g4[i] = *(const v4f*)(sGf + e * 128 + wm * 64 + i * 16 + lk * 4);

      const unsigned char* pbe =
          bptr + (size_t)e * HD + (size_t)kt * 128;
      __builtin_amdgcn_s_setprio(1);
#pragma unroll
      for (int j = 0; j < 4; ++j) {
        const unsigned char* pb = pbe + (size_t)j * (16 * DDIM);
        union { v8i v; v4i h[2]; } u;
        u.h[0] = *(const v4i*)(pb);
        u.h[1] = *(const v4i*)(pb + 16);
        const v8i bv = u.v;
#pragma unroll
        for (int i = 0; i < 4; ++i) {
          const v4f t = __builtin_amdgcn_mfma_scale_f32_16x16x128_f8f6f4(
              av[i], bv, zero4, 0 /*fp8*/, 0 /*fp8*/,
              0, 127 /*e8m0 1.0*/, 0, 127 /*e8m0 1.0*/);
          outacc[i][j][0] += g4[i][0] * t[0];
          outacc[i][j][1] += g4[i][1] * t[1];
          outacc[i][j][2] += g4[i][2] * t[2];
          outacc[i][j][3] += g4[i][3] * t[3];
        }
      }
      __builtin_amdgcn_s_setprio(0);
    }
  }

#undef STAGE_A

  // epilogue: direct coalesced stores (single block per output tile)
#pragma unroll
  for (int i = 0; i < 4; ++i)
#pragma unroll
    for (int q = 0; q < 4; ++q) {
      const size_t r = (size_t)(bm + wm * 64 + i * 16 + lk * 4 + q);
      float* orow = out + r * HDIM + bn + wn * 64 + lrow;
#pragma unroll
      for (int j = 0; j < 4; ++j)
        orow[j * 16] = outacc[i][j][q];
    }
}

extern "C" void kernel_launch(void* const* d_in, const int* in_sizes, int n_in,
                              void* d_out, int out_size, void* d_ws, size_t ws_size,
                              hipStream_t stream) {
  (void)in_sizes; (void)n_in; (void)out_size; (void)ws_size;
  const float* x        = (const float*)d_in[0];
  const float* gate_w   = (const float*)d_in[1];
  const float* gate_b   = (const float*)d_in[2];
  const float* expert_w = (const float*)d_in[3];
  float* out = (float*)d_out;

  char* ws = (char*)d_ws;
  float* gate       = (float*)ws;                                   // 131072 B
  unsigned char* x8 = (unsigned char*)(ws + 131072);                // 8 MiB
  unsigned char* w8 = (unsigned char*)(ws + 131072 + (size_t)MDIM * DDIM);

  hipLaunchKernelGGL(k_gate_xq, dim3(MDIM / 4), dim3(256), 0, stream,
                     x, gate_w, gate_b, gate, x8);
  hipLaunchKernelGGL(k_wq, dim3(4096), dim3(256), 0, stream, expert_w, w8);
  hipLaunchKernelGGL(k_moe_gemm, dim3(512), dim3(256), 36864, stream,
                     x8, w8, gate, out);
}

// Round 14
// 1415.533 us; speedup vs baseline: 2.1356x; 2.1015x over previous
//
#include <hip/hip_runtime.h>
#include <hip/hip_bf16.h>

#define MDIM 4096
#define DDIM 2048
#define HDIM 2048
#define EDIM 8
#define HD   ((size_t)HDIM * DDIM)

typedef float v4f __attribute__((ext_vector_type(4)));
typedef int   v4i __attribute__((ext_vector_type(4)));
typedef int   v8i __attribute__((ext_vector_type(8)));

// async global->LDS, 16B per lane. lds pointer must be wave-uniform
// (HW writes base + lane*16).
__device__ __forceinline__ void gl2lds16(const void* g, void* l) {
  __builtin_amdgcn_global_load_lds(
      (const __attribute__((address_space(1))) void*)g,
      (__attribute__((address_space(3))) void*)l,
      16, 0, 0);
}

// ---------------- Kernel 1: gating softmax + fp8 quantize of x ----------------
__global__ __launch_bounds__(256) void k_gate_xq(
    const float* __restrict__ x, const float* __restrict__ gw,
    const float* __restrict__ gb, float* __restrict__ gate,
    unsigned char* __restrict__ x8)
{
  const int wid  = threadIdx.x >> 6;
  const int lane = threadIdx.x & 63;
  const int m    = blockIdx.x * 4 + wid;

  const float4* xr = (const float4*)(x + (size_t)m * DDIM);
  unsigned int* qr = (unsigned int*)(x8 + (size_t)m * DDIM);

  float part[EDIM];
#pragma unroll
  for (int e = 0; e < EDIM; ++e) part[e] = 0.f;

#pragma unroll
  for (int it = 0; it < DDIM / 4 / 64; ++it) {   // 8 iterations
    const int idx = it * 64 + lane;
    const float4 xv = xr[idx];
    int pk = __builtin_amdgcn_cvt_pk_fp8_f32(xv.x, xv.y, 0, false);
    pk = __builtin_amdgcn_cvt_pk_fp8_f32(xv.z, xv.w, pk, true);
    qr[idx] = (unsigned int)pk;
#pragma unroll
    for (int e = 0; e < EDIM; ++e) {
      const float4 wv = ((const float4*)(gw + (size_t)e * DDIM))[idx];
      part[e] += xv.x * wv.x + xv.y * wv.y + xv.z * wv.z + xv.w * wv.w;
    }
  }
#pragma unroll
  for (int e = 0; e < EDIM; ++e) {
#pragma unroll
    for (int off = 32; off > 0; off >>= 1)
      part[e] += __shfl_xor(part[e], off);
  }
  float lg[EDIM];
  float s = 0.f;
#pragma unroll
  for (int e = 0; e < EDIM; ++e) lg[e] = part[e] + gb[e];
  float mx = lg[0];
#pragma unroll
  for (int e = 1; e < EDIM; ++e) mx = fmaxf(mx, lg[e]);
#pragma unroll
  for (int e = 0; e < EDIM; ++e) { lg[e] = expf(lg[e] - mx); s += lg[e]; }
  const float inv = 1.f / s;
  if (lane < EDIM) gate[m * EDIM + lane] = lg[lane] * inv;
}

// ---------------- Kernel 2: fp8 quantize of expert_w --------------------------
__global__ void k_wq(const float* __restrict__ w, unsigned char* __restrict__ w8)
{
  const long long n4 = (long long)EDIM * HDIM * DDIM / 4;
  const long long stride = (long long)gridDim.x * blockDim.x;
  for (long long i = (long long)blockIdx.x * blockDim.x + threadIdx.x; i < n4;
       i += stride) {
    const float4 v = ((const float4*)w)[i];
    int pk = __builtin_amdgcn_cvt_pk_fp8_f32(v.x, v.y, 0, false);
    pk = __builtin_amdgcn_cvt_pk_fp8_f32(v.z, v.w, pk, true);
    ((unsigned int*)w8)[i] = (unsigned int)pk;
  }
}

// ---------------- Kernel 3: fused grouped GEMM + gated combine ----------------
// R13 structure, ONE variable changed: __launch_bounds__(256, 2) -> (256, 1).
// Register model (R5..R13, 9 data points): under a 2-waves/SIMD floor the
// unified 256-reg budget splits FIXED 128 arch + 128 AGPR when MFMA is
// present; any design with >128 arch-reg demand spills GBs to scratch at
// VGPR_Count == 128 exactly (R6,R7,R8,R9,R12,R13). Under (256,1) the budget
// is 512 (R10: 232 arch, clean). This kernel's zero-C mfma + VALU gate-FMA
// needs ~180-220 arch -> needs the 512 budget.
// Structure: A staged in LDS (dbuf, global_load_lds, both-sides XOR swizzle,
// ONCE per k-tile -- 8x less A staging than R11); B direct global->VGPR in a
// fence-free expert loop (16 barriers total vs R11's 256); per-(kt,e)
// gate-FMA outacc += g_e * mfma(A,B_e,0) (absmax 0.015625, 4x validated).
__global__ __launch_bounds__(256, 1) void k_moe_gemm(
    const unsigned char* __restrict__ x8,   // [M, D]
    const unsigned char* __restrict__ w8,   // [E, H, D]
    const float* __restrict__ gate,         // [M, 8]
    float* __restrict__ out)                // [M, H] f32
{
  extern __shared__ unsigned char smem[];   // 2*16K A + 4K gates = 36864 B

  const int tid  = threadIdx.x;
  const int lane = tid & 63;
  const int wid  = tid >> 6;        // 0..3
  const int wm   = wid >> 1;        // 0..1  (64-row group)
  const int wn   = wid & 1;         // 0..1  (64-col group)

  // XCD chunking: 512 blocks; each XCD owns an 8x8 square of (m,h) tiles.
  const int bid   = blockIdx.x;
  const int xcd   = bid & 7;
  const int local = bid >> 3;                        // 0..63
  const int tm    = (xcd >> 1) * 8 + (local >> 3);   // 0..31
  const int tn    = (xcd & 1) * 8 + (local & 7);     // 0..15
  const int bm    = tm * 128;
  const int bn    = tn * 128;

  const int lrow = lane & 15;
  const int lk   = lane >> 4;                  // 0..3 -> 32B k-block
  const int c0   = (lk * 32) ^ ((lrow & 7) << 4);   // swizzled A read cols
  const int c1   = c0 ^ 16;

  // A staging coords (inverse-swizzled source; LDS dest linear)
  const int strow = tid >> 3;                  // 0..31
  const int stcol = ((tid & 7) * 16) ^ ((strow & 7) << 4);
  const unsigned char* asrc = x8 + (size_t)(bm + strow) * DDIM + stcol;

  // B fragment base pointer (per lane, direct global)
  const unsigned char* bptr =
      w8 + (size_t)(bn + wn * 64 + lrow) * DDIM + lk * 32;

  float* sGf = (float*)(smem + 32768);         // [8 experts][128 rows]

  // gate cache: threads 0..127 own row bm+tid for all 8 experts
  if (tid < 128) {
    const float4 g0 = *(const float4*)(gate + (size_t)(bm + tid) * EDIM);
    const float4 g1 = *(const float4*)(gate + (size_t)(bm + tid) * EDIM + 4);
    sGf[0 * 128 + tid] = g0.x; sGf[1 * 128 + tid] = g0.y;
    sGf[2 * 128 + tid] = g0.z; sGf[3 * 128 + tid] = g0.w;
    sGf[4 * 128 + tid] = g1.x; sGf[5 * 128 + tid] = g1.y;
    sGf[6 * 128 + tid] = g1.z; sGf[7 * 128 + tid] = g1.w;
  }

  v4f outacc[4][4];   // gated running sum
#pragma unroll
  for (int i = 0; i < 4; ++i)
#pragma unroll
    for (int j = 0; j < 4; ++j) {
      outacc[i][j][0] = 0.f; outacc[i][j][1] = 0.f;
      outacc[i][j][2] = 0.f; outacc[i][j][3] = 0.f;
    }
  const v4f zero4 = {0.f, 0.f, 0.f, 0.f};

// stage A k-tile KT into abuf[KT&1]: 4 gl2lds16/thread
#define STAGE_A(KT) do {                                                       \
    const int kb_ = (KT) * 128;                                                \
    unsigned char* la_ = smem + ((KT) & 1) * 16384;                            \
    _Pragma("unroll") for (int i = 0; i < 4; ++i)                              \
      gl2lds16(asrc + (size_t)i * (32 * DDIM) + kb_,                           \
               (void*)(la_ + i * 4096 + wid * 1024));                          \
  } while (0)

  // prologue: stage A(0); publish gates; drain
  STAGE_A(0);
  __syncthreads();

  for (int kt = 0; kt < 16; ++kt) {
    // A(kt) loads were issued a full k-tile ago; all B loads already consumed.
    asm volatile("s_waitcnt vmcnt(0)" ::: "memory");
    __builtin_amdgcn_s_barrier();

    // A fragments for this k-tile (intra-region; crosses no fence)
    v8i av[4];
    {
      const unsigned char* pA = smem + (kt & 1) * 16384 +
                                (size_t)(wm * 64 + lrow) * 128;
#pragma unroll
      for (int f = 0; f < 4; ++f) {
        union { v8i v; v4i h[2]; } u;
        u.h[0] = *(const v4i*)(pA + f * 2048 + c0);
        u.h[1] = *(const v4i*)(pA + f * 2048 + c1);
        av[f] = u.v;
      }
    }
    if (kt < 15) STAGE_A(kt + 1);   // strictly after barrier(kt): race-free

    // fence-free expert loop: direct-global B + mfma + gate-FMA
#pragma unroll
    for (int e = 0; e < EDIM; ++e) {
      v4f g4[4];
#pragma unroll
      for (int i = 0; i < 4; ++i)
        g4[i] = *(const v4f*)(sGf + e * 128 + wm * 64 + i * 16 + lk * 4);

      const unsigned char* pbe =
          bptr + (size_t)e * HD + (size_t)kt * 128;
      __builtin_amdgcn_s_setprio(1);
#pragma unroll
      for (int j = 0; j < 4; ++j) {
        const unsigned char* pb = pbe + (size_t)j * (16 * DDIM);
        union { v8i v; v4i h[2]; } u;
        u.h[0] = *(const v4i*)(pb);
        u.h[1] = *(const v4i*)(pb + 16);
        const v8i bv = u.v;
#pragma unroll
        for (int i = 0; i < 4; ++i) {
          const v4f t = __builtin_amdgcn_mfma_scale_f32_16x16x128_f8f6f4(
              av[i], bv, zero4, 0 /*fp8*/, 0 /*fp8*/,
              0, 127 /*e8m0 1.0*/, 0, 127 /*e8m0 1.0*/);
          outacc[i][j][0] += g4[i][0] * t[0];
          outacc[i][j][1] += g4[i][1] * t[1];
          outacc[i][j][2] += g4[i][2] * t[2];
          outacc[i][j][3] += g4[i][3] * t[3];
        }
      }
      __builtin_amdgcn_s_setprio(0);
    }
  }

#undef STAGE_A

  // epilogue: direct coalesced stores (single block per output tile)
#pragma unroll
  for (int i = 0; i < 4; ++i)
#pragma unroll
    for (int q = 0; q < 4; ++q) {
      const size_t r = (size_t)(bm + wm * 64 + i * 16 + lk * 4 + q);
      float* orow = out + r * HDIM + bn + wn * 64 + lrow;
#pragma unroll
      for (int j = 0; j < 4; ++j)
        orow[j * 16] = outacc[i][j][q];
    }
}

extern "C" void kernel_launch(void* const* d_in, const int* in_sizes, int n_in,
                              void* d_out, int out_size, void* d_ws, size_t ws_size,
                              hipStream_t stream) {
  (void)in_sizes; (void)n_in; (void)out_size; (void)ws_size;
  const float* x        = (const float*)d_in[0];
  const float* gate_w   = (const float*)d_in[1];
  const float* gate_b   = (const float*)d_in[2];
  const float* expert_w = (const float*)d_in[3];
  float* out = (float*)d_out;

  char* ws = (char*)d_ws;
  float* gate       = (float*)ws;                                   // 131072 B
  unsigned char* x8 = (unsigned char*)(ws + 131072);                // 8 MiB
  unsigned char* w8 = (unsigned char*)(ws + 131072 + (size_t)MDIM * DDIM);

  hipLaunchKernelGGL(k_gate_xq, dim3(MDIM / 4), dim3(256), 0, stream,
                     x, gate_w, gate_b, gate, x8);
  hipLaunchKernelGGL(k_wq, dim3(4096), dim3(256), 0, stream, expert_w, w8);
  hipLaunchKernelGGL(k_moe_gemm, dim3(512), dim3(256), 36864, stream,
                     x8, w8, gate, out);
}

// Round 15
// 318.893 us; speedup vs baseline: 9.4797x; 4.4389x over previous
//
#include <hip/hip_runtime.h>
#include <hip/hip_bf16.h>

#define MDIM 4096
#define DDIM 2048
#define HDIM 2048
#define EDIM 8
#define HD   ((size_t)HDIM * DDIM)

typedef float v4f __attribute__((ext_vector_type(4)));
typedef int   v4i __attribute__((ext_vector_type(4)));
typedef int   v8i __attribute__((ext_vector_type(8)));

// async global->LDS, 16B per lane. lds pointer must be wave-uniform
// (HW writes base + lane*16).
__device__ __forceinline__ void gl2lds16(const void* g, void* l) {
  __builtin_amdgcn_global_load_lds(
      (const __attribute__((address_space(1))) void*)g,
      (__attribute__((address_space(3))) void*)l,
      16, 0, 0);
}

// ---------------- Kernel 1: gating softmax + fp8 quantize of x ----------------
__global__ __launch_bounds__(256) void k_gate_xq(
    const float* __restrict__ x, const float* __restrict__ gw,
    const float* __restrict__ gb, float* __restrict__ gate,
    unsigned char* __restrict__ x8)
{
  const int wid  = threadIdx.x >> 6;
  const int lane = threadIdx.x & 63;
  const int m    = blockIdx.x * 4 + wid;

  const float4* xr = (const float4*)(x + (size_t)m * DDIM);
  unsigned int* qr = (unsigned int*)(x8 + (size_t)m * DDIM);

  float part[EDIM];
#pragma unroll
  for (int e = 0; e < EDIM; ++e) part[e] = 0.f;

#pragma unroll
  for (int it = 0; it < DDIM / 4 / 64; ++it) {   // 8 iterations
    const int idx = it * 64 + lane;
    const float4 xv = xr[idx];
    int pk = __builtin_amdgcn_cvt_pk_fp8_f32(xv.x, xv.y, 0, false);
    pk = __builtin_amdgcn_cvt_pk_fp8_f32(xv.z, xv.w, pk, true);
    qr[idx] = (unsigned int)pk;
#pragma unroll
    for (int e = 0; e < EDIM; ++e) {
      const float4 wv = ((const float4*)(gw + (size_t)e * DDIM))[idx];
      part[e] += xv.x * wv.x + xv.y * wv.y + xv.z * wv.z + xv.w * wv.w;
    }
  }
#pragma unroll
  for (int e = 0; e < EDIM; ++e) {
#pragma unroll
    for (int off = 32; off > 0; off >>= 1)
      part[e] += __shfl_xor(part[e], off);
  }
  float lg[EDIM];
  float s = 0.f;
#pragma unroll
  for (int e = 0; e < EDIM; ++e) lg[e] = part[e] + gb[e];
  float mx = lg[0];
#pragma unroll
  for (int e = 1; e < EDIM; ++e) mx = fmaxf(mx, lg[e]);
#pragma unroll
  for (int e = 0; e < EDIM; ++e) { lg[e] = expf(lg[e] - mx); s += lg[e]; }
  const float inv = 1.f / s;
  if (lane < EDIM) gate[m * EDIM + lane] = lg[lane] * inv;
}

// ---------------- Kernel 2: fp8 quantize of expert_w --------------------------
__global__ void k_wq(const float* __restrict__ w, unsigned char* __restrict__ w8)
{
  const long long n4 = (long long)EDIM * HDIM * DDIM / 4;
  const long long stride = (long long)gridDim.x * blockDim.x;
  for (long long i = (long long)blockIdx.x * blockDim.x + threadIdx.x; i < n4;
       i += stride) {
    const float4 v = ((const float4*)w)[i];
    int pk = __builtin_amdgcn_cvt_pk_fp8_f32(v.x, v.y, 0, false);
    pk = __builtin_amdgcn_cvt_pk_fp8_f32(v.z, v.w, pk, true);
    ((unsigned int*)w8)[i] = (unsigned int)pk;
  }
}

// ---------------- Kernel 3: fused grouped GEMM + gated combine ----------------
// R11's register discipline + R13's barrier skeleton + direct-global B:
//  - e-outer linear steps s = e*16 + kt (dynamic loop, NOT unrolled ->
//    one-step scheduling regions bound register pressure; R14's hoisting
//    blowup structurally excluded).
//  - acc[4][4] C-CHAINED mfma accumulator (AGPR half of the unified file) +
//    outacc[4][4] folded with the gate at expert boundaries (R11-proven:
//    arch ~100 < the 128-arch half available at 2 waves/SIMD).
//  - A staged in LDS (dbuf global_load_lds, both-sides XOR swizzle); B reads
//    DIRECT global->VGPR in COMP (L1/L2-resident under XCD chunking). LDS
//    read traffic per step halves vs R11 (its measured wall), B staging and
//    its barrier pressure disappear.
//  - ONE barrier per step: vmcnt(0) -> s_barrier -> STAGE_A(s+1) -> COMP(s).
//    Safe: abuf[(s+1)&1] was last read in COMP(s-1), and every wave passed
//    barrier(s) after finishing COMP(s-1).
// 256 thr (4 waves 2m x 2n, 64x64/wave), tile 128x128, grid 512 = 2
// independent blocks/CU (stall interleave). absmax path identical to R11.
__global__ __launch_bounds__(256, 2) void k_moe_gemm(
    const unsigned char* __restrict__ x8,   // [M, D]
    const unsigned char* __restrict__ w8,   // [E, H, D]
    const float* __restrict__ gate,         // [M, 8]
    float* __restrict__ out)                // [M, H] f32
{
  extern __shared__ unsigned char smem[];   // 2*16K A + 4K gates = 36864 B

  const int tid  = threadIdx.x;
  const int lane = tid & 63;
  const int wid  = tid >> 6;        // 0..3
  const int wm   = wid >> 1;        // 0..1  (64-row group)
  const int wn   = wid & 1;         // 0..1  (64-col group)

  // XCD chunking: 512 blocks; each XCD owns an 8x8 square of (m,h) tiles.
  const int bid   = blockIdx.x;
  const int xcd   = bid & 7;
  const int local = bid >> 3;                        // 0..63
  const int tm    = (xcd >> 1) * 8 + (local >> 3);   // 0..31
  const int tn    = (xcd & 1) * 8 + (local & 7);     // 0..15
  const int bm    = tm * 128;
  const int bn    = tn * 128;

  const int lrow = lane & 15;
  const int lk   = lane >> 4;                  // 0..3 -> 32B k-block
  const int c0   = (lk * 32) ^ ((lrow & 7) << 4);   // swizzled A read cols
  const int c1   = c0 ^ 16;

  // A staging coords (inverse-swizzled source; LDS dest linear)
  const int strow = tid >> 3;                  // 0..31
  const int stcol = ((tid & 7) * 16) ^ ((strow & 7) << 4);
  const unsigned char* asrc = x8 + (size_t)(bm + strow) * DDIM + stcol;

  // B fragment base pointer (per lane, direct global)
  const unsigned char* bptr =
      w8 + (size_t)(bn + wn * 64 + lrow) * DDIM + lk * 32;

  float* sGf = (float*)(smem + 32768);         // [8 experts][128 rows]

  // gate cache: threads 0..127 own row bm+tid for all 8 experts
  if (tid < 128) {
    const float4 g0 = *(const float4*)(gate + (size_t)(bm + tid) * EDIM);
    const float4 g1 = *(const float4*)(gate + (size_t)(bm + tid) * EDIM + 4);
    sGf[0 * 128 + tid] = g0.x; sGf[1 * 128 + tid] = g0.y;
    sGf[2 * 128 + tid] = g0.z; sGf[3 * 128 + tid] = g0.w;
    sGf[4 * 128 + tid] = g1.x; sGf[5 * 128 + tid] = g1.y;
    sGf[6 * 128 + tid] = g1.z; sGf[7 * 128 + tid] = g1.w;
  }

  v4f acc[4][4];      // per-expert partial, mfma C-chained (AGPR)
  v4f outacc[4][4];   // gated running sum (AGPR-foldable)
#pragma unroll
  for (int i = 0; i < 4; ++i)
#pragma unroll
    for (int j = 0; j < 4; ++j) {
      acc[i][j][0] = 0.f; acc[i][j][1] = 0.f;
      acc[i][j][2] = 0.f; acc[i][j][3] = 0.f;
      outacc[i][j][0] = 0.f; outacc[i][j][1] = 0.f;
      outacc[i][j][2] = 0.f; outacc[i][j][3] = 0.f;
    }

// stage A k-tile of step S into abuf[S&1]: 4 gl2lds16/thread
#define STAGE_A(S) do {                                                        \
    const int kb_ = ((S) & 15) * 128;                                          \
    unsigned char* la_ = smem + ((S) & 1) * 16384;                             \
    _Pragma("unroll") for (int i = 0; i < 4; ++i)                              \
      gl2lds16(asrc + (size_t)i * (32 * DDIM) + kb_,                           \
               (void*)(la_ + i * 4096 + wid * 1024));                          \
  } while (0)

  // prologue: stage A(0); publish gates; drain
  STAGE_A(0);
  __syncthreads();

  for (int s = 0; s < 128; ++s) {
    // A(s) was issued one step ago (or in prologue); drain and sync.
    asm volatile("s_waitcnt vmcnt(0)" ::: "memory");
    __builtin_amdgcn_s_barrier();
    if (s < 127) STAGE_A(s + 1);   // after barrier: abuf[(s+1)&1] is free

    // A fragments from LDS (swizzled reads)
    v8i av[4];
    {
      const unsigned char* pA = smem + (s & 1) * 16384 +
                                (size_t)(wm * 64 + lrow) * 128;
#pragma unroll
      for (int f = 0; f < 4; ++f) {
        union { v8i v; v4i h[2]; } u;
        u.h[0] = *(const v4i*)(pA + f * 2048 + c0);
        u.h[1] = *(const v4i*)(pA + f * 2048 + c1);
        av[f] = u.v;
      }
    }

    // B fragments direct from global (L1/L2), C-chained MFMA
    const int e  = s >> 4;
    const int kt = s & 15;
    const unsigned char* pbe = bptr + (size_t)e * HD + (size_t)kt * 128;
    __builtin_amdgcn_s_setprio(1);
#pragma unroll
    for (int j = 0; j < 4; ++j) {
      const unsigned char* pb = pbe + (size_t)j * (16 * DDIM);
      union { v8i v; v4i h[2]; } u;
      u.h[0] = *(const v4i*)(pb);
      u.h[1] = *(const v4i*)(pb + 16);
      const v8i bv = u.v;
#pragma unroll
      for (int i = 0; i < 4; ++i)
        acc[i][j] = __builtin_amdgcn_mfma_scale_f32_16x16x128_f8f6f4(
            av[i], bv, acc[i][j], 0 /*fp8*/, 0 /*fp8*/,
            0, 127 /*e8m0 1.0*/, 0, 127 /*e8m0 1.0*/);
    }
    __builtin_amdgcn_s_setprio(0);

    // expert boundary: fold gate into outacc, reset acc
    if ((s & 15) == 15) {
#pragma unroll
      for (int i = 0; i < 4; ++i) {
        const v4f g4 =
            *(const v4f*)(sGf + e * 128 + wm * 64 + i * 16 + lk * 4);
#pragma unroll
        for (int j = 0; j < 4; ++j) {
          outacc[i][j][0] += g4[0] * acc[i][j][0]; acc[i][j][0] = 0.f;
          outacc[i][j][1] += g4[1] * acc[i][j][1]; acc[i][j][1] = 0.f;
          outacc[i][j][2] += g4[2] * acc[i][j][2]; acc[i][j][2] = 0.f;
          outacc[i][j][3] += g4[3] * acc[i][j][3]; acc[i][j][3] = 0.f;
        }
      }
    }
  }

#undef STAGE_A

  // epilogue: direct coalesced stores (single block per output tile)
#pragma unroll
  for (int i = 0; i < 4; ++i)
#pragma unroll
    for (int q = 0; q < 4; ++q) {
      const size_t r = (size_t)(bm + wm * 64 + i * 16 + lk * 4 + q);
      float* orow = out + r * HDIM + bn + wn * 64 + lrow;
#pragma unroll
      for (int j = 0; j < 4; ++j)
        orow[j * 16] = outacc[i][j][q];
    }
}

extern "C" void kernel_launch(void* const* d_in, const int* in_sizes, int n_in,
                              void* d_out, int out_size, void* d_ws, size_t ws_size,
                              hipStream_t stream) {
  (void)in_sizes; (void)n_in; (void)out_size; (void)ws_size;
  const float* x        = (const float*)d_in[0];
  const float* gate_w   = (const float*)d_in[1];
  const float* gate_b   = (const float*)d_in[2];
  const float* expert_w = (const float*)d_in[3];
  float* out = (float*)d_out;

  char* ws = (char*)d_ws;
  float* gate       = (float*)ws;                                   // 131072 B
  unsigned char* x8 = (unsigned char*)(ws + 131072);                // 8 MiB
  unsigned char* w8 = (unsigned char*)(ws + 131072 + (size_t)MDIM * DDIM);

  hipLaunchKernelGGL(k_gate_xq, dim3(MDIM / 4), dim3(256), 0, stream,
                     x, gate_w, gate_b, gate, x8);
  hipLaunchKernelGGL(k_wq, dim3(4096), dim3(256), 0, stream, expert_w, w8);
  hipLaunchKernelGGL(k_moe_gemm, dim3(512), dim3(256), 36864, stream,
                     x8, w8, gate, out);
}